// Round 18
// baseline (346.752 us; speedup 1.0000x reference)
//
#include <hip/hip_runtime.h>
#include <math.h>

#define NN 100000
#define NE 1600000
#define NCH 98           // ceil(NN/1024)
#define PROJ_BLOCKS 3125 // 4 waves/block, 8 rows/wave: 3125*4*8 = NN exactly
#define SCAT_GRID 1024

__device__ __forceinline__ float lrelu(float t) { return t >= 0.0f ? t : 0.2f * t; }

// count in-degree (2 edges/thread); record each edge's arrival rank
// (rank makes the scatter atomic-free — r16 proved with-return tickets 3x worse)
__global__ __launch_bounds__(256) void k_count(
    const int* __restrict__ ei, int* __restrict__ cnt, int* __restrict__ rank) {
    int e = (blockIdx.x * 256 + threadIdx.x) * 2;
    if (e < NE) {
        int2 d = *(const int2*)(ei + NE + e);
        rank[e]     = atomicAdd(&cnt[d.x], 1);
        rank[e + 1] = atomicAdd(&cnt[d.y], 1);
    }
}

// in-place exclusive scan of cnt per 1024-chunk; chunk totals to part[]
__global__ __launch_bounds__(1024) void k_scan1(int* __restrict__ cnt, int* __restrict__ part) {
    __shared__ int s[1024];
    int tid = threadIdx.x, i = blockIdx.x * 1024 + tid;
    int v = (i < NN) ? cnt[i] : 0;
    s[tid] = v; __syncthreads();
    for (int off = 1; off < 1024; off <<= 1) {
        int t = (tid >= off) ? s[tid - off] : 0; __syncthreads();
        s[tid] += t; __syncthreads();
    }
    if (i < NN) cnt[i] = s[tid] - v;                 // exclusive within chunk
    if (tid == 1023) part[blockIdx.x] = s[1023];     // chunk total
}

// exclusive scan of the 98 chunk totals (one block); rowptr[n] is then
// computed on the fly everywhere as cnt[n] + part[n>>10]
__global__ __launch_bounds__(128) void k_scanp(int* __restrict__ part) {
    __shared__ int s[128];
    int tid = threadIdx.x;
    int v = (tid < NCH) ? part[tid] : 0;
    s[tid] = v; __syncthreads();
    for (int off = 1; off < 128; off <<= 1) {
        int t = (tid >= off) ? s[tid - off] : 0; __syncthreads();
        s[tid] += t; __syncthreads();
    }
    if (tid < NCH) part[tid] = s[tid] - v;           // exclusive
}

// atomic-free CSR scatter: slot = cnt[d] + part[d>>10] + rank[e]
__global__ __launch_bounds__(256) void k_scatter(
    const int* __restrict__ ei, const int* __restrict__ cnt,
    const int* __restrict__ part, const int* __restrict__ rank,
    int* __restrict__ csr) {
    int t = blockIdx.x * 256 + threadIdx.x;
    const int S = SCAT_GRID * 256;
    #pragma unroll 4
    for (int e = t; e < NE; e += S) {
        int d = ei[NE + e];
        csr[cnt[d] + part[d >> 10] + rank[e]] = ei[e];
    }
}

// proj: h = x @ W^T (fp32, W row in registers, pipelined LDS reads);
// att logits fused (fp32 16-lane head reduce).
__global__ __launch_bounds__(256) void k_proj(
    const float* __restrict__ x, const float* __restrict__ pw,
    const float* __restrict__ atts, const float* __restrict__ attd,
    float* __restrict__ h, float* __restrict__ asrc, float* __restrict__ adst) {
    __shared__ __align__(16) float w[64][68];
    __shared__ __align__(16) float xs[4][68];
    int tid = threadIdx.x;
    for (int i = tid; i < 4096; i += 256) w[i >> 6][i & 63] = pw[i];
    int lane = tid & 63, wv = tid >> 6;
    float aw = atts[lane], dw = attd[lane];
    __syncthreads();
    float4 wr[16];
    #pragma unroll
    for (int j = 0; j < 16; ++j) wr[j] = *(const float4*)&w[lane][4 * j];
    for (int base = blockIdx.x * 4; base < NN; base += PROJ_BLOCKS * 4) {
        int row = base + wv;
        bool ok = row < NN;
        xs[wv][lane] = ok ? x[row * 64 + lane] : 0.0f;   // same-wave LDS
        float4 xv0 = *(const float4*)&xs[wv][0];
        float4 xv1 = *(const float4*)&xs[wv][4];
        float4 xv2 = *(const float4*)&xs[wv][8];
        float4 xv3 = *(const float4*)&xs[wv][12];
        float a0 = 0, a1 = 0, a2 = 0, a3 = 0;
#define Q(J, XV) do { \
        float4 xq = XV; \
        if ((J) < 12) XV = *(const float4*)&xs[wv][4 * ((J) + 4)]; \
        a0 += wr[J].x * xq.x; \
        a1 += wr[J].y * xq.y; \
        a2 += wr[J].z * xq.z; \
        a3 += wr[J].w * xq.w; \
    } while (0)
        Q(0, xv0);  Q(1, xv1);  Q(2, xv2);  Q(3, xv3);
        Q(4, xv0);  Q(5, xv1);  Q(6, xv2);  Q(7, xv3);
        Q(8, xv0);  Q(9, xv1);  Q(10, xv2); Q(11, xv3);
        Q(12, xv0); Q(13, xv1); Q(14, xv2); Q(15, xv3);
#undef Q
        float hf = (a0 + a1) + (a2 + a3);
        float s = hf * aw, d = hf * dw;
        #pragma unroll
        for (int off = 8; off; off >>= 1) {              // 16-lane head reduce
            s += __shfl_xor(s, off);
            d += __shfl_xor(d, off);
        }
        if (ok) {
            h[row * 64 + lane] = hf;
            if ((lane & 15) == 0) {
                asrc[row * 4 + (lane >> 4)] = s;
                adst[row * 4 + (lane >> 4)] = d;
            }
        }
    }
}

// Fused gather+softmax+aggregate+GEMM+norm+threshold: ONE wave per node.
// lane = 16*eg + cg. Edge-group eg owns edges {4G + eg : 4G < deg}.
// No max subtraction (shift-invariant, |logit| <= ~4). After the eg-reduce
// the am row goes to a 1KB same-wave LDS tile; the wave then applies po
// (rows in registers, loaded from L1-resident global) + norm + threshold.
__global__ __launch_bounds__(256) void k_agg(
    const int* __restrict__ cnt, const int* __restrict__ part,
    const int* __restrict__ csr,
    const float* __restrict__ asrc, const float* __restrict__ adst,
    const float* __restrict__ h, const float* __restrict__ po,
    const float* __restrict__ gamma, const float* __restrict__ beta,
    float* __restrict__ out) {
    __shared__ __align__(16) float ams[4][64];
    int tid = threadIdx.x;
    int lane = tid & 63, wv = tid >> 6;
    int cg = lane & 15, hh = cg >> 2, eg = lane >> 4;
    const int n = blockIdx.x * 4 + wv;           // grid 25000 * 4 waves = NN exactly

    int r0 = cnt[n] + part[n >> 10];
    int r1 = (n + 1 < NN) ? cnt[n + 1] + part[(n + 1) >> 10] : NE;
    int deg = r1 - r0;
    float4 bd = *(const float4*)(adst + (size_t)n * 4);  // wave-uniform
    int se = (lane < deg) ? csr[r0 + lane] : 0;

#define HLOAD(S) (*(const float4*)(h + ((size_t)(S) << 6) + (cg << 2)))
    if (deg <= 64) {
        float4 fb0 = HLOAD(__shfl(se, eg));      // edges eg, 4+eg, 8+eg, 12+eg in flight
        float4 fb1 = HLOAD(__shfl(se, eg + 4));
        float4 fb2 = HLOAD(__shfl(se, eg + 8));
        float4 fb3 = HLOAD(__shfl(se, eg + 12));

        float4 ex = make_float4(0.f, 0.f, 0.f, 0.f);
        if (lane < deg) {
            float4 av = *(const float4*)(asrc + (size_t)se * 4);
            ex.x = expf(lrelu(av.x + bd.x));
            ex.y = expf(lrelu(av.y + bd.y));
            ex.z = expf(lrelu(av.z + bd.z));
            ex.w = expf(lrelu(av.w + bd.w));
        }

        float ac0 = 0, ac1 = 0, ac2 = 0, ac3 = 0, ds = 0;
#define STEP(G, FB) do { if (4 * (G) < deg) { \
        int src_ = 4 * (G) + eg; \
        float axx = __shfl(ex.x, src_); \
        float axy = __shfl(ex.y, src_); \
        float axz = __shfl(ex.z, src_); \
        float axw = __shfl(ex.w, src_); \
        float a_ = hh < 2 ? (hh == 0 ? axx : axy) : (hh == 2 ? axz : axw); \
        float4 fv_ = FB; \
        if (4 * ((G) + 4) < deg) { int sr_ = __shfl(se, src_ + 16); FB = HLOAD(sr_); } \
        ds  += a_; \
        ac0 += a_ * fv_.x; ac1 += a_ * fv_.y; \
        ac2 += a_ * fv_.z; ac3 += a_ * fv_.w; \
    } } while (0)
        STEP(0, fb0);  STEP(1, fb1);  STEP(2, fb2);  STEP(3, fb3);
        STEP(4, fb0);  STEP(5, fb1);  STEP(6, fb2);  STEP(7, fb3);
        STEP(8, fb0);  STEP(9, fb1);  STEP(10, fb2); STEP(11, fb3);
        STEP(12, fb0); STEP(13, fb1); STEP(14, fb2); STEP(15, fb3);
#undef STEP
        // fp32 reduce over the 4 edge-groups (lanes cg, 16+cg, 32+cg, 48+cg)
        ac0 += __shfl_xor(ac0, 32); ac1 += __shfl_xor(ac1, 32);
        ac2 += __shfl_xor(ac2, 32); ac3 += __shfl_xor(ac3, 32);
        ds  += __shfl_xor(ds, 32);
        ac0 += __shfl_xor(ac0, 16); ac1 += __shfl_xor(ac1, 16);
        ac2 += __shfl_xor(ac2, 16); ac3 += __shfl_xor(ac3, 16);
        ds  += __shfl_xor(ds, 16);
        if (eg == 0) {                           // 16 lanes write the full am row
            float sc = (1.0f / (ds + 1e-16f)) * (1.0f / (float)(deg > 0 ? deg : 1));
            float4 amv = make_float4(ac0 * sc, ac1 * sc, ac2 * sc, ac3 * sc);
            *(float4*)&ams[wv][4 * cg] = amv;    // same-wave LDS, no barrier
        }
    } else {
        // rare fallback (deg>64): lane = channel, serial edges (no max, same math)
        int hd = lane >> 4;
        float bdh = hd == 0 ? bd.x : hd == 1 ? bd.y : hd == 2 ? bd.z : bd.w;
        float den = 0.0f, aA = 0.0f;
        for (int e2 = 0; e2 < deg; ++e2) {
            int s = csr[r0 + e2];
            float ee = expf(lrelu(asrc[(size_t)s * 4 + hd] + bdh));
            den += ee;
            aA += ee * h[(size_t)s * 64 + lane];
        }
        ams[wv][lane] = aA / (den + 1e-16f) / (float)deg;
    }
#undef HLOAD

    // ---- fused GEMM (po row in registers from L1-resident global) ----
    float4 wr[16];
    #pragma unroll
    for (int j = 0; j < 16; ++j) wr[j] = *(const float4*)(po + (size_t)lane * 64 + 4 * j);
    float b0 = 0, b1 = 0, b2 = 0, b3 = 0;
    #pragma unroll
    for (int j = 0; j < 16; ++j) {
        float4 amv = *(const float4*)&ams[wv][4 * j];   // b128 broadcast
        b0 += wr[j].x * amv.x; b1 += wr[j].y * amv.y;
        b2 += wr[j].z * amv.z; b3 += wr[j].w * amv.w;
    }
    float a2 = (b0 + b1) + (b2 + b3);
    // per-node norm (fp32 butterflies) + threshold
    float sum = a2;
    #pragma unroll
    for (int off = 32; off; off >>= 1) sum += __shfl_xor(sum, off);
    float mean = sum * (1.0f / 64.0f);
    float dv = a2 - mean, sq = dv * dv;
    #pragma unroll
    for (int off = 32; off; off >>= 1) sq += __shfl_xor(sq, off);
    float var = sq * (1.0f / 64.0f);
    float z = dv / sqrtf(var + 1e-5f);
    float zf = z * gamma[lane] + beta[lane];
    out[(size_t)n * 64 + lane] = (zf >= 2.0f) ? 1.0f : 0.0f;  // LIF fwd == z >= 2
}

extern "C" void kernel_launch(void* const* d_in, const int* in_sizes, int n_in,
                              void* d_out, int out_size, void* d_ws, size_t ws_size,
                              hipStream_t stream) {
    const float* x     = (const float*)d_in[0];
    const int*   ei    = (const int*)d_in[1];   // harness pushes integers as int32
    const float* pw    = (const float*)d_in[2];
    const float* po    = (const float*)d_in[3];
    const float* atts  = (const float*)d_in[4];
    const float* attd  = (const float*)d_in[5];
    const float* gamma = (const float*)d_in[6];
    const float* beta  = (const float*)d_in[7];
    float* out = (float*)d_out;

    char* base = (char*)d_ws;
    size_t off = 0;
    auto alloc = [&](size_t b) { void* p = base + off; off += (b + 255) & ~(size_t)255; return p; };
    float* h    = (float*)alloc((size_t)NN * 64 * 4);
    float* asrc = (float*)alloc((size_t)NN * 16);
    float* adst = (float*)alloc((size_t)NN * 16);
    int*   cnt  = (int*)alloc((size_t)NN * 4);   // in ws: must outlive k_agg's out writes
    int*   csr  = (int*)alloc((size_t)NE * 4);
    int*   rank = (int*)alloc((size_t)NE * 4);
    int*   part = (int*)alloc((size_t)NCH * 4);

    hipMemsetAsync(cnt, 0, (size_t)NN * 4, stream);
    k_count<<<NE / 512, 256, 0, stream>>>(ei, cnt, rank);
    k_scan1<<<NCH, 1024, 0, stream>>>(cnt, part);
    k_scanp<<<1, 128, 0, stream>>>(part);
    k_scatter<<<SCAT_GRID, 256, 0, stream>>>(ei, cnt, part, rank, csr);
    k_proj<<<PROJ_BLOCKS, 256, 0, stream>>>(x, pw, atts, attd, h, asrc, adst);
    k_agg<<<NN / 4, 256, 0, stream>>>(cnt, part, csr, asrc, adst, h, po, gamma, beta, out);
}

// Round 19
// 237.087 us; speedup vs baseline: 1.4626x; 1.4626x over previous
//
#include <hip/hip_runtime.h>
#include <math.h>

#define NN 100000
#define NE 1600000
#define NCH 98           // ceil(NN/1024)
#define PROJ_BLOCKS 3125 // 4 waves/block, 8 rows/wave: 3125*4*8 = NN exactly
#define SCAT_GRID 1024

__device__ __forceinline__ float lrelu(float t) { return t >= 0.0f ? t : 0.2f * t; }

// count in-degree (2 edges/thread); record each edge's arrival rank
// (rank makes the scatter atomic-free — r16 proved with-return tickets 3x worse)
__global__ __launch_bounds__(256) void k_count(
    const int* __restrict__ ei, int* __restrict__ cnt, int* __restrict__ rank) {
    int e = (blockIdx.x * 256 + threadIdx.x) * 2;
    if (e < NE) {
        int2 d = *(const int2*)(ei + NE + e);
        rank[e]     = atomicAdd(&cnt[d.x], 1);
        rank[e + 1] = atomicAdd(&cnt[d.y], 1);
    }
}

// in-place exclusive scan of cnt per 1024-chunk; chunk totals to part[]
__global__ __launch_bounds__(1024) void k_scan1(int* __restrict__ cnt, int* __restrict__ part) {
    __shared__ int s[1024];
    int tid = threadIdx.x, i = blockIdx.x * 1024 + tid;
    int v = (i < NN) ? cnt[i] : 0;
    s[tid] = v; __syncthreads();
    for (int off = 1; off < 1024; off <<= 1) {
        int t = (tid >= off) ? s[tid - off] : 0; __syncthreads();
        s[tid] += t; __syncthreads();
    }
    if (i < NN) cnt[i] = s[tid] - v;                 // exclusive within chunk
    if (tid == 1023) part[blockIdx.x] = s[1023];     // chunk total
}

// exclusive scan of the 98 chunk totals (one block); rowptr[n] computed
// on the fly everywhere as cnt[n] + part[n>>10]
__global__ __launch_bounds__(128) void k_scanp(int* __restrict__ part) {
    __shared__ int s[128];
    int tid = threadIdx.x;
    int v = (tid < NCH) ? part[tid] : 0;
    s[tid] = v; __syncthreads();
    for (int off = 1; off < 128; off <<= 1) {
        int t = (tid >= off) ? s[tid - off] : 0; __syncthreads();
        s[tid] += t; __syncthreads();
    }
    if (tid < NCH) part[tid] = s[tid] - v;           // exclusive
}

// atomic-free CSR scatter: slot = cnt[d] + part[d>>10] + rank[e]
__global__ __launch_bounds__(256) void k_scatter(
    const int* __restrict__ ei, const int* __restrict__ cnt,
    const int* __restrict__ part, const int* __restrict__ rank,
    int* __restrict__ csr) {
    int t = blockIdx.x * 256 + threadIdx.x;
    const int S = SCAT_GRID * 256;
    #pragma unroll 4
    for (int e = t; e < NE; e += S) {
        int d = ei[NE + e];
        csr[cnt[d] + part[d >> 10] + rank[e]] = ei[e];
    }
}

// proj: h = x @ W^T (fp32, W row in registers, pipelined LDS reads);
// att logits fused (fp32 16-lane head reduce).
__global__ __launch_bounds__(256) void k_proj(
    const float* __restrict__ x, const float* __restrict__ pw,
    const float* __restrict__ atts, const float* __restrict__ attd,
    float* __restrict__ h, float* __restrict__ asrc, float* __restrict__ adst) {
    __shared__ __align__(16) float w[64][68];
    __shared__ __align__(16) float xs[4][68];
    int tid = threadIdx.x;
    for (int i = tid; i < 4096; i += 256) w[i >> 6][i & 63] = pw[i];
    int lane = tid & 63, wv = tid >> 6;
    float aw = atts[lane], dw = attd[lane];
    __syncthreads();
    float4 wr[16];
    #pragma unroll
    for (int j = 0; j < 16; ++j) wr[j] = *(const float4*)&w[lane][4 * j];
    for (int base = blockIdx.x * 4; base < NN; base += PROJ_BLOCKS * 4) {
        int row = base + wv;
        bool ok = row < NN;
        xs[wv][lane] = ok ? x[row * 64 + lane] : 0.0f;   // same-wave LDS
        float4 xv0 = *(const float4*)&xs[wv][0];
        float4 xv1 = *(const float4*)&xs[wv][4];
        float4 xv2 = *(const float4*)&xs[wv][8];
        float4 xv3 = *(const float4*)&xs[wv][12];
        float a0 = 0, a1 = 0, a2 = 0, a3 = 0;
#define Q(J, XV) do { \
        float4 xq = XV; \
        if ((J) < 12) XV = *(const float4*)&xs[wv][4 * ((J) + 4)]; \
        a0 += wr[J].x * xq.x; \
        a1 += wr[J].y * xq.y; \
        a2 += wr[J].z * xq.z; \
        a3 += wr[J].w * xq.w; \
    } while (0)
        Q(0, xv0);  Q(1, xv1);  Q(2, xv2);  Q(3, xv3);
        Q(4, xv0);  Q(5, xv1);  Q(6, xv2);  Q(7, xv3);
        Q(8, xv0);  Q(9, xv1);  Q(10, xv2); Q(11, xv3);
        Q(12, xv0); Q(13, xv1); Q(14, xv2); Q(15, xv3);
#undef Q
        float hf = (a0 + a1) + (a2 + a3);
        float s = hf * aw, d = hf * dw;
        #pragma unroll
        for (int off = 8; off; off >>= 1) {              // 16-lane head reduce
            s += __shfl_xor(s, off);
            d += __shfl_xor(d, off);
        }
        if (ok) {
            h[row * 64 + lane] = hf;
            if ((lane & 15) == 0) {
                asrc[row * 4 + (lane >> 4)] = s;
                adst[row * 4 + (lane >> 4)] = d;
            }
        }
    }
}

// Fused gather+softmax+aggregate+GEMM+norm+threshold: ONE wave per node.
// lane = 16*eg + cg. Edge-group eg owns edges {4G + eg : 4G < deg}.
// No max subtraction (shift-invariant, |logit| <= ~4).
// po staged coalesced into LDS once per block (r17 k_gemm pattern — the r18
// per-lane global po reads were the regression); GEMM phase reads per-lane
// b128 from LDS + b128 ams broadcast.
__global__ __launch_bounds__(256) void k_agg(
    const int* __restrict__ cnt, const int* __restrict__ part,
    const int* __restrict__ csr,
    const float* __restrict__ asrc, const float* __restrict__ adst,
    const float* __restrict__ h, const float* __restrict__ po,
    const float* __restrict__ gamma, const float* __restrict__ beta,
    float* __restrict__ out) {
    __shared__ __align__(16) float w[64][68];
    __shared__ __align__(16) float ams[4][64];
    int tid = threadIdx.x;
    for (int i = tid; i < 4096; i += 256) w[i >> 6][i & 63] = po[i];
    int lane = tid & 63, wv = tid >> 6;
    int cg = lane & 15, hh = cg >> 2, eg = lane >> 4;
    const int n = blockIdx.x * 4 + wv;           // grid 25000 * 4 waves = NN exactly

    int r0 = cnt[n] + part[n >> 10];
    int r1 = (n + 1 < NN) ? cnt[n + 1] + part[(n + 1) >> 10] : NE;
    int deg = r1 - r0;
    float4 bd = *(const float4*)(adst + (size_t)n * 4);  // wave-uniform
    int se = (lane < deg) ? csr[r0 + lane] : 0;
    __syncthreads();                              // w staged

#define HLOAD(S) (*(const float4*)(h + ((size_t)(S) << 6) + (cg << 2)))
    if (deg <= 64) {
        float4 fb0 = HLOAD(__shfl(se, eg));      // edges eg, 4+eg, 8+eg, 12+eg in flight
        float4 fb1 = HLOAD(__shfl(se, eg + 4));
        float4 fb2 = HLOAD(__shfl(se, eg + 8));
        float4 fb3 = HLOAD(__shfl(se, eg + 12));

        float4 ex = make_float4(0.f, 0.f, 0.f, 0.f);
        if (lane < deg) {
            float4 av = *(const float4*)(asrc + (size_t)se * 4);
            ex.x = expf(lrelu(av.x + bd.x));
            ex.y = expf(lrelu(av.y + bd.y));
            ex.z = expf(lrelu(av.z + bd.z));
            ex.w = expf(lrelu(av.w + bd.w));
        }

        float ac0 = 0, ac1 = 0, ac2 = 0, ac3 = 0, ds = 0;
#define STEP(G, FB) do { if (4 * (G) < deg) { \
        int src_ = 4 * (G) + eg; \
        float axx = __shfl(ex.x, src_); \
        float axy = __shfl(ex.y, src_); \
        float axz = __shfl(ex.z, src_); \
        float axw = __shfl(ex.w, src_); \
        float a_ = hh < 2 ? (hh == 0 ? axx : axy) : (hh == 2 ? axz : axw); \
        float4 fv_ = FB; \
        if (4 * ((G) + 4) < deg) { int sr_ = __shfl(se, src_ + 16); FB = HLOAD(sr_); } \
        ds  += a_; \
        ac0 += a_ * fv_.x; ac1 += a_ * fv_.y; \
        ac2 += a_ * fv_.z; ac3 += a_ * fv_.w; \
    } } while (0)
        STEP(0, fb0);  STEP(1, fb1);  STEP(2, fb2);  STEP(3, fb3);
        STEP(4, fb0);  STEP(5, fb1);  STEP(6, fb2);  STEP(7, fb3);
        STEP(8, fb0);  STEP(9, fb1);  STEP(10, fb2); STEP(11, fb3);
        STEP(12, fb0); STEP(13, fb1); STEP(14, fb2); STEP(15, fb3);
#undef STEP
        // fp32 reduce over the 4 edge-groups (lanes cg, 16+cg, 32+cg, 48+cg)
        ac0 += __shfl_xor(ac0, 32); ac1 += __shfl_xor(ac1, 32);
        ac2 += __shfl_xor(ac2, 32); ac3 += __shfl_xor(ac3, 32);
        ds  += __shfl_xor(ds, 32);
        ac0 += __shfl_xor(ac0, 16); ac1 += __shfl_xor(ac1, 16);
        ac2 += __shfl_xor(ac2, 16); ac3 += __shfl_xor(ac3, 16);
        ds  += __shfl_xor(ds, 16);
        if (eg == 0) {                           // 16 lanes write the full am row
            float sc = (1.0f / (ds + 1e-16f)) * (1.0f / (float)(deg > 0 ? deg : 1));
            float4 amv = make_float4(ac0 * sc, ac1 * sc, ac2 * sc, ac3 * sc);
            *(float4*)&ams[wv][4 * cg] = amv;    // same-wave LDS, no barrier
        }
    } else {
        // rare fallback (deg>64): lane = channel, serial edges (no max, same math)
        int hd = lane >> 4;
        float bdh = hd == 0 ? bd.x : hd == 1 ? bd.y : hd == 2 ? bd.z : bd.w;
        float den = 0.0f, aA = 0.0f;
        for (int e2 = 0; e2 < deg; ++e2) {
            int s = csr[r0 + e2];
            float ee = expf(lrelu(asrc[(size_t)s * 4 + hd] + bdh));
            den += ee;
            aA += ee * h[(size_t)s * 64 + lane];
        }
        ams[wv][lane] = aA / (den + 1e-16f) / (float)deg;
    }
#undef HLOAD

    // ---- fused GEMM: per-lane b128 reads of w from LDS + b128 ams broadcast
    float b0 = 0, b1 = 0, b2 = 0, b3 = 0;
    #pragma unroll
    for (int j = 0; j < 16; ++j) {
        float4 wv4 = *(const float4*)&w[lane][4 * j];   // per-lane b128 (LDS)
        float4 amv = *(const float4*)&ams[wv][4 * j];   // b128 broadcast
        b0 += wv4.x * amv.x; b1 += wv4.y * amv.y;
        b2 += wv4.z * amv.z; b3 += wv4.w * amv.w;
    }
    float a2 = (b0 + b1) + (b2 + b3);
    // per-node norm (fp32 butterflies) + threshold
    float sum = a2;
    #pragma unroll
    for (int off = 32; off; off >>= 1) sum += __shfl_xor(sum, off);
    float mean = sum * (1.0f / 64.0f);
    float dv = a2 - mean, sq = dv * dv;
    #pragma unroll
    for (int off = 32; off; off >>= 1) sq += __shfl_xor(sq, off);
    float var = sq * (1.0f / 64.0f);
    float z = dv / sqrtf(var + 1e-5f);
    float zf = z * gamma[lane] + beta[lane];
    out[(size_t)n * 64 + lane] = (zf >= 2.0f) ? 1.0f : 0.0f;  // LIF fwd == z >= 2
}

extern "C" void kernel_launch(void* const* d_in, const int* in_sizes, int n_in,
                              void* d_out, int out_size, void* d_ws, size_t ws_size,
                              hipStream_t stream) {
    const float* x     = (const float*)d_in[0];
    const int*   ei    = (const int*)d_in[1];   // harness pushes integers as int32
    const float* pw    = (const float*)d_in[2];
    const float* po    = (const float*)d_in[3];
    const float* atts  = (const float*)d_in[4];
    const float* attd  = (const float*)d_in[5];
    const float* gamma = (const float*)d_in[6];
    const float* beta  = (const float*)d_in[7];
    float* out = (float*)d_out;

    char* base = (char*)d_ws;
    size_t off = 0;
    auto alloc = [&](size_t b) { void* p = base + off; off += (b + 255) & ~(size_t)255; return p; };
    float* h    = (float*)alloc((size_t)NN * 64 * 4);
    float* asrc = (float*)alloc((size_t)NN * 16);
    float* adst = (float*)alloc((size_t)NN * 16);
    int*   cnt  = (int*)alloc((size_t)NN * 4);   // in ws: must outlive k_agg's out writes
    int*   csr  = (int*)alloc((size_t)NE * 4);
    int*   rank = (int*)alloc((size_t)NE * 4);
    int*   part = (int*)alloc((size_t)NCH * 4);

    hipMemsetAsync(cnt, 0, (size_t)NN * 4, stream);
    k_count<<<NE / 512, 256, 0, stream>>>(ei, cnt, rank);
    k_scan1<<<NCH, 1024, 0, stream>>>(cnt, part);
    k_scanp<<<1, 128, 0, stream>>>(part);
    k_scatter<<<SCAT_GRID, 256, 0, stream>>>(ei, cnt, part, rank, csr);
    k_proj<<<PROJ_BLOCKS, 256, 0, stream>>>(x, pw, atts, attd, h, asrc, adst);
    k_agg<<<NN / 4, 256, 0, stream>>>(cnt, part, csr, asrc, adst, h, po, gamma, beta, out);
}

// Round 21
// 236.806 us; speedup vs baseline: 1.4643x; 1.0012x over previous
//
#include <hip/hip_runtime.h>
#include <math.h>

#define NN 100000
#define NE 1600000
#define NCH 98           // ceil(NN/1024)
#define PROJ_BLOCKS 3125 // 4 waves/block, 8 rows/wave: 3125*4*8 = NN exactly

__device__ __forceinline__ float lrelu(float t) { return t >= 0.0f ? t : 0.2f * t; }

// count in-degree (4 edges/thread, int4); record each edge's arrival rank
// (rank makes the scatter atomic-free — r16 proved with-return tickets 3x worse)
__global__ __launch_bounds__(256) void k_count(
    const int* __restrict__ ei, int* __restrict__ cnt, int* __restrict__ rank) {
    int e = (blockIdx.x * 256 + threadIdx.x) * 4;
    if (e < NE) {                                // NE % 4 == 0: all-or-none
        int4 d = *(const int4*)(ei + NE + e);
        rank[e]     = atomicAdd(&cnt[d.x], 1);
        rank[e + 1] = atomicAdd(&cnt[d.y], 1);
        rank[e + 2] = atomicAdd(&cnt[d.z], 1);
        rank[e + 3] = atomicAdd(&cnt[d.w], 1);
    }
}

// in-place exclusive scan of cnt per 1024-chunk; chunk totals to part[]
__global__ __launch_bounds__(1024) void k_scan1(int* __restrict__ cnt, int* __restrict__ part) {
    __shared__ int s[1024];
    int tid = threadIdx.x, i = blockIdx.x * 1024 + tid;
    int v = (i < NN) ? cnt[i] : 0;
    s[tid] = v; __syncthreads();
    for (int off = 1; off < 1024; off <<= 1) {
        int t = (tid >= off) ? s[tid - off] : 0; __syncthreads();
        s[tid] += t; __syncthreads();
    }
    if (i < NN) cnt[i] = s[tid] - v;                 // exclusive within chunk
    if (tid == 1023) part[blockIdx.x] = s[1023];     // chunk total
}

// exclusive scan of the 98 chunk totals (one block); rowptr[n] computed
// on the fly everywhere as cnt[n] + part[n>>10]
__global__ __launch_bounds__(128) void k_scanp(int* __restrict__ part) {
    __shared__ int s[128];
    int tid = threadIdx.x;
    int v = (tid < NCH) ? part[tid] : 0;
    s[tid] = v; __syncthreads();
    for (int off = 1; off < 128; off <<= 1) {
        int t = (tid >= off) ? s[tid - off] : 0; __syncthreads();
        s[tid] += t; __syncthreads();
    }
    if (tid < NCH) part[tid] = s[tid] - v;           // exclusive
}

// atomic-free CSR scatter: 1 edge/thread, max TLP for the latency-bound
// random 4B writes (slot = cnt[d] + part[d>>10] + rank[e])
__global__ __launch_bounds__(256) void k_scatter(
    const int* __restrict__ ei, const int* __restrict__ cnt,
    const int* __restrict__ part, const int* __restrict__ rank,
    int* __restrict__ csr) {
    int e = blockIdx.x * 256 + threadIdx.x;
    if (e < NE) {
        int d = ei[NE + e];
        csr[cnt[d] + part[d >> 10] + rank[e]] = ei[e];
    }
}

// proj: h = x @ W^T (fp32, W row in registers, pipelined LDS reads);
// att logits fused (fp32 16-lane head reduce).
__global__ __launch_bounds__(256) void k_proj(
    const float* __restrict__ x, const float* __restrict__ pw,
    const float* __restrict__ atts, const float* __restrict__ attd,
    float* __restrict__ h, float* __restrict__ asrc, float* __restrict__ adst) {
    __shared__ __align__(16) float w[64][68];
    __shared__ __align__(16) float xs[4][68];
    int tid = threadIdx.x;
    for (int i = tid; i < 4096; i += 256) w[i >> 6][i & 63] = pw[i];
    int lane = tid & 63, wv = tid >> 6;
    float aw = atts[lane], dw = attd[lane];
    __syncthreads();
    float4 wr[16];
    #pragma unroll
    for (int j = 0; j < 16; ++j) wr[j] = *(const float4*)&w[lane][4 * j];
    for (int base = blockIdx.x * 4; base < NN; base += PROJ_BLOCKS * 4) {
        int row = base + wv;
        bool ok = row < NN;
        xs[wv][lane] = ok ? x[row * 64 + lane] : 0.0f;   // same-wave LDS
        float4 xv0 = *(const float4*)&xs[wv][0];
        float4 xv1 = *(const float4*)&xs[wv][4];
        float4 xv2 = *(const float4*)&xs[wv][8];
        float4 xv3 = *(const float4*)&xs[wv][12];
        float a0 = 0, a1 = 0, a2 = 0, a3 = 0;
#define Q(J, XV) do { \
        float4 xq = XV; \
        if ((J) < 12) XV = *(const float4*)&xs[wv][4 * ((J) + 4)]; \
        a0 += wr[J].x * xq.x; \
        a1 += wr[J].y * xq.y; \
        a2 += wr[J].z * xq.z; \
        a3 += wr[J].w * xq.w; \
    } while (0)
        Q(0, xv0);  Q(1, xv1);  Q(2, xv2);  Q(3, xv3);
        Q(4, xv0);  Q(5, xv1);  Q(6, xv2);  Q(7, xv3);
        Q(8, xv0);  Q(9, xv1);  Q(10, xv2); Q(11, xv3);
        Q(12, xv0); Q(13, xv1); Q(14, xv2); Q(15, xv3);
#undef Q
        float hf = (a0 + a1) + (a2 + a3);
        float s = hf * aw, d = hf * dw;
        #pragma unroll
        for (int off = 8; off; off >>= 1) {              // 16-lane head reduce
            s += __shfl_xor(s, off);
            d += __shfl_xor(d, off);
        }
        if (ok) {
            h[row * 64 + lane] = hf;
            if ((lane & 15) == 0) {
                asrc[row * 4 + (lane >> 4)] = s;
                adst[row * 4 + (lane >> 4)] = d;
            }
        }
    }
}

// Fused gather+softmax+aggregate+GEMM+norm+threshold: ONE wave per node.
// lane = 16*eg + cg. Edge-group eg owns edges {4G + eg : 4G < deg}.
// No max subtraction (shift-invariant, |logit| <= ~4). po staged coalesced
// into LDS once per block; GEMM reads per-lane b128 + b128 ams broadcast.
__global__ __launch_bounds__(256) void k_agg(
    const int* __restrict__ cnt, const int* __restrict__ part,
    const int* __restrict__ csr,
    const float* __restrict__ asrc, const float* __restrict__ adst,
    const float* __restrict__ h, const float* __restrict__ po,
    const float* __restrict__ gamma, const float* __restrict__ beta,
    float* __restrict__ out) {
    __shared__ __align__(16) float w[64][68];
    __shared__ __align__(16) float ams[4][64];
    int tid = threadIdx.x;
    for (int i = tid; i < 4096; i += 256) w[i >> 6][i & 63] = po[i];
    int lane = tid & 63, wv = tid >> 6;
    int cg = lane & 15, hh = cg >> 2, eg = lane >> 4;
    const int n = blockIdx.x * 4 + wv;           // grid 25000 * 4 waves = NN exactly

    int r0 = cnt[n] + part[n >> 10];
    int r1 = (n + 1 < NN) ? cnt[n + 1] + part[(n + 1) >> 10] : NE;
    int deg = r1 - r0;
    float4 bd = *(const float4*)(adst + (size_t)n * 4);  // wave-uniform
    int se = (lane < deg) ? csr[r0 + lane] : 0;
    __syncthreads();                              // w staged

#define HLOAD(S) (*(const float4*)(h + ((size_t)(S) << 6) + (cg << 2)))
    if (deg <= 64) {
        float4 fb0 = HLOAD(__shfl(se, eg));      // edges eg, 4+eg, 8+eg, 12+eg in flight
        float4 fb1 = HLOAD(__shfl(se, eg + 4));
        float4 fb2 = HLOAD(__shfl(se, eg + 8));
        float4 fb3 = HLOAD(__shfl(se, eg + 12));

        float4 ex = make_float4(0.f, 0.f, 0.f, 0.f);
        if (lane < deg) {
            float4 av = *(const float4*)(asrc + (size_t)se * 4);
            ex.x = expf(lrelu(av.x + bd.x));
            ex.y = expf(lrelu(av.y + bd.y));
            ex.z = expf(lrelu(av.z + bd.z));
            ex.w = expf(lrelu(av.w + bd.w));
        }

        float ac0 = 0, ac1 = 0, ac2 = 0, ac3 = 0, ds = 0;
#define STEP(G, FB) do { if (4 * (G) < deg) { \
        int src_ = 4 * (G) + eg; \
        float axx = __shfl(ex.x, src_); \
        float axy = __shfl(ex.y, src_); \
        float axz = __shfl(ex.z, src_); \
        float axw = __shfl(ex.w, src_); \
        float a_ = hh < 2 ? (hh == 0 ? axx : axy) : (hh == 2 ? axz : axw); \
        float4 fv_ = FB; \
        if (4 * ((G) + 4) < deg) { int sr_ = __shfl(se, src_ + 16); FB = HLOAD(sr_); } \
        ds  += a_; \
        ac0 += a_ * fv_.x; ac1 += a_ * fv_.y; \
        ac2 += a_ * fv_.z; ac3 += a_ * fv_.w; \
    } } while (0)
        STEP(0, fb0);  STEP(1, fb1);  STEP(2, fb2);  STEP(3, fb3);
        STEP(4, fb0);  STEP(5, fb1);  STEP(6, fb2);  STEP(7, fb3);
        STEP(8, fb0);  STEP(9, fb1);  STEP(10, fb2); STEP(11, fb3);
        STEP(12, fb0); STEP(13, fb1); STEP(14, fb2); STEP(15, fb3);
#undef STEP
        // fp32 reduce over the 4 edge-groups (lanes cg, 16+cg, 32+cg, 48+cg)
        ac0 += __shfl_xor(ac0, 32); ac1 += __shfl_xor(ac1, 32);
        ac2 += __shfl_xor(ac2, 32); ac3 += __shfl_xor(ac3, 32);
        ds  += __shfl_xor(ds, 32);
        ac0 += __shfl_xor(ac0, 16); ac1 += __shfl_xor(ac1, 16);
        ac2 += __shfl_xor(ac2, 16); ac3 += __shfl_xor(ac3, 16);
        ds  += __shfl_xor(ds, 16);
        if (eg == 0) {                           // 16 lanes write the full am row
            float sc = (1.0f / (ds + 1e-16f)) * (1.0f / (float)(deg > 0 ? deg : 1));
            float4 amv = make_float4(ac0 * sc, ac1 * sc, ac2 * sc, ac3 * sc);
            *(float4*)&ams[wv][4 * cg] = amv;    // same-wave LDS, no barrier
        }
    } else {
        // rare fallback (deg>64): lane = channel, serial edges (no max, same math)
        int hd = lane >> 4;
        float bdh = hd == 0 ? bd.x : hd == 1 ? bd.y : hd == 2 ? bd.z : bd.w;
        float den = 0.0f, aA = 0.0f;
        for (int e2 = 0; e2 < deg; ++e2) {
            int s = csr[r0 + e2];
            float ee = expf(lrelu(asrc[(size_t)s * 4 + hd] + bdh));
            den += ee;
            aA += ee * h[(size_t)s * 64 + lane];
        }
        ams[wv][lane] = aA / (den + 1e-16f) / (float)deg;
    }
#undef HLOAD

    // ---- fused GEMM: per-lane b128 reads of w from LDS + b128 ams broadcast
    float b0 = 0, b1 = 0, b2 = 0, b3 = 0;
    #pragma unroll
    for (int j = 0; j < 16; ++j) {
        float4 wv4 = *(const float4*)&w[lane][4 * j];   // per-lane b128 (LDS)
        float4 amv = *(const float4*)&ams[wv][4 * j];   // b128 broadcast
        b0 += wv4.x * amv.x; b1 += wv4.y * amv.y;
        b2 += wv4.z * amv.z; b3 += wv4.w * amv.w;
    }
    float a2 = (b0 + b1) + (b2 + b3);
    // per-node norm (fp32 butterflies) + threshold
    float sum = a2;
    #pragma unroll
    for (int off = 32; off; off >>= 1) sum += __shfl_xor(sum, off);
    float mean = sum * (1.0f / 64.0f);
    float dv = a2 - mean, sq = dv * dv;
    #pragma unroll
    for (int off = 32; off; off >>= 1) sq += __shfl_xor(sq, off);
    float var = sq * (1.0f / 64.0f);
    float z = dv / sqrtf(var + 1e-5f);
    float zf = z * gamma[lane] + beta[lane];
    out[(size_t)n * 64 + lane] = (zf >= 2.0f) ? 1.0f : 0.0f;  // LIF fwd == z >= 2
}

extern "C" void kernel_launch(void* const* d_in, const int* in_sizes, int n_in,
                              void* d_out, int out_size, void* d_ws, size_t ws_size,
                              hipStream_t stream) {
    const float* x     = (const float*)d_in[0];
    const int*   ei    = (const int*)d_in[1];   // harness pushes integers as int32
    const float* pw    = (const float*)d_in[2];
    const float* po    = (const float*)d_in[3];
    const float* atts  = (const float*)d_in[4];
    const float* attd  = (const float*)d_in[5];
    const float* gamma = (const float*)d_in[6];
    const float* beta  = (const float*)d_in[7];
    float* out = (float*)d_out;

    char* base = (char*)d_ws;
    size_t off = 0;
    auto alloc = [&](size_t b) { void* p = base + off; off += (b + 255) & ~(size_t)255; return p; };
    float* h    = (float*)alloc((size_t)NN * 64 * 4);
    float* asrc = (float*)alloc((size_t)NN * 16);
    float* adst = (float*)alloc((size_t)NN * 16);
    int*   cnt  = (int*)alloc((size_t)NN * 4);   // in ws: must outlive k_agg's out writes
    int*   csr  = (int*)alloc((size_t)NE * 4);
    int*   rank = (int*)alloc((size_t)NE * 4);
    int*   part = (int*)alloc((size_t)NCH * 4);

    hipMemsetAsync(cnt, 0, (size_t)NN * 4, stream);
    k_count<<<(NE / 4 + 255) / 256, 256, 0, stream>>>(ei, cnt, rank);  // ceil! (r20 bug: NE/1024 truncated)
    k_scan1<<<NCH, 1024, 0, stream>>>(cnt, part);
    k_scanp<<<1, 128, 0, stream>>>(part);
    k_scatter<<<NE / 256, 256, 0, stream>>>(ei, cnt, part, rank, csr);
    k_proj<<<PROJ_BLOCKS, 256, 0, stream>>>(x, pw, atts, attd, h, asrc, adst);
    k_agg<<<NN / 4, 256, 0, stream>>>(cnt, part, csr, asrc, adst, h, po, gamma, beta, out);
}